// Round 5
// baseline (320.137 us; speedup 1.0000x reference)
//
#include <hip/hip_runtime.h>
#include <math.h>

#define SD 768
#define SB 16
#define SM 8
#define SS 2048
#define TOK_ROW 2049
#define NEG_INF (-__builtin_inff())

// ws layout (float offsets). Total 1,122,432 floats = 4.5 MB.
// ptradS stat-major:
//   [0,12288)      sum accumulators (fadd, init 0)
//   [12288,24576)  max accumulators (uint-encoded, atomicMax, init 0x00000000)
//   [24576,36864)  min accumulators (uint-encoded, atomicMin, init 0xFFFFFFFF)
#define OFF_PTRADS  0          // 3*16*768
#define OFF_PLEARN  36864      // 16*6912 (merged: fadd init 0; clf: plain store)
#define OFF_LTOT    147456     // 16*8 (fadd init 0)
#define OFF_LNSTAT  147584     // 16*2048*2 (mu, rstd per row; no init needed)
#define OFF_P1A     213120     // 18*12288
#define OFF_P1B     434304     // 54*12288
#define OFF_HA      1097856    // 12288
#define OFF_HB      1110144    // 12288

__device__ __forceinline__ int clen(int v) { return v < 1 ? 1 : (v > SS ? SS : v); }

// order-preserving float<->uint encoding: f1 < f2  <=>  fenc(f1) < fenc(f2) (unsigned)
__device__ __forceinline__ unsigned fenc(float f) {
  unsigned u = __float_as_uint(f);
  return (u & 0x80000000u) ? ~u : (u ^ 0x80000000u);
}
__device__ __forceinline__ float fdec(unsigned u) {
  unsigned i = (u & 0x80000000u) ? (u ^ 0x80000000u) : ~u;
  return __uint_as_float(i);
}

// ============ init: accumulator identities + bias into out ====================
__global__ void k_init(float* __restrict__ ws, float* __restrict__ out,
                       const float* __restrict__ b2a, const float* __restrict__ b2b) {
  int i = blockIdx.x * 256 + threadIdx.x;
  int stride = gridDim.x * 256;
  for (int t = i; t < 147584; t += stride) {
    unsigned v = (t >= 24576 && t < 36864) ? 0xFFFFFFFFu : 0u;
    ((unsigned*)ws)[t] = v;
  }
  for (int t = i; t < 24576; t += stride) {
    int b = t / 1536, r = t - b * 1536;
    out[t] = (r < 768) ? b2a[r] : b2b[r - 768];
  }
}

// ============ K_pool: streaming pool partials + LN stats ======================
// grid (32 chunks of 64 rows, 16 b), 4 waves; wave w owns rows [c*64+16w,+16).
// No LDS -> high occupancy. Pool merged via per-wave device atomics.
// Also computes per-row LN mu/rstd -> lnstat (consumed by k_score).
__global__ __launch_bounds__(256) void k_pool(
    const float* __restrict__ tokens, const int* __restrict__ lengths,
    float* __restrict__ ptradS, float* __restrict__ lnstat) {
  int c = blockIdx.x, b = blockIdx.y;
  int len = clen(lengths[b]);
  int c0 = c * 64;
  if (c0 >= len) return;
  int tid = threadIdx.x, w = tid >> 6, lane = tid & 63;

  float psum[12], pmax[12], pmin[12];
  #pragma unroll
  for (int j = 0; j < 12; ++j) { psum[j] = 0.f; pmax[j] = NEG_INF; pmin[j] = -NEG_INF; }

  int srow = c0 + w * 16;
  int smax = len - srow; if (smax > 16) smax = 16; if (smax < 0) smax = 0;
  const float* xrow = tokens + ((size_t)b * TOK_ROW + 1 + srow) * SD;

  float4 nx0 = {}, nx1 = {}, nx2 = {};
  if (smax > 0) {
    nx0 = *(const float4*)(xrow + lane * 4);
    nx1 = *(const float4*)(xrow + 256 + lane * 4);
    nx2 = *(const float4*)(xrow + 512 + lane * 4);
  }
  for (int i = 0; i < smax; ++i) {
    float4 x0 = nx0, x1 = nx1, x2 = nx2;
    if (i + 1 < smax) {
      const float* xq = xrow + (size_t)(i + 1) * SD;
      nx0 = *(const float4*)(xq + lane * 4);
      nx1 = *(const float4*)(xq + 256 + lane * 4);
      nx2 = *(const float4*)(xq + 512 + lane * 4);
    }
    float xv[12] = {x0.x, x0.y, x0.z, x0.w, x1.x, x1.y, x1.z, x1.w,
                    x2.x, x2.y, x2.z, x2.w};
    float s1 = 0.f, s2 = 0.f;
    #pragma unroll
    for (int j = 0; j < 12; ++j) {
      float v = xv[j];
      psum[j] += v;
      pmax[j] = fmaxf(pmax[j], v);
      pmin[j] = fminf(pmin[j], v);
      s1 += v;
      s2 += v * v;
    }
    #pragma unroll
    for (int o = 1; o <= 32; o <<= 1) { s1 += __shfl_xor(s1, o, 64); s2 += __shfl_xor(s2, o, 64); }
    float mu = s1 * (1.f / 768.f);
    float var = s2 * (1.f / 768.f) - mu * mu;
    float rstd = rsqrtf(var + 1e-5f);
    if (lane == 0) {
      size_t ro = ((size_t)b * SS + srow + i) * 2;
      lnstat[ro] = mu;
      lnstat[ro + 1] = rstd;
    }
  }

  // per-wave atomic merge into ptradS
  #pragma unroll
  for (int j = 0; j < 12; ++j) {
    int ch = (j >> 2) * 256 + lane * 4 + (j & 3);
    atomicAdd(&ptradS[b * 768 + ch], psum[j]);
    atomicMax((unsigned*)&ptradS[12288 + b * 768 + ch], fenc(pmax[j]));
    atomicMin((unsigned*)&ptradS[24576 + b * 768 + ch], fenc(pmin[j]));
  }
}

// ============ K_score: scores + exp + O_c, occupancy-optimized ===============
// grid (32 chunks of 64 rows, 16 b), 4 waves; wave w owns rows [c*64+16w,+16).
// q fragments: m=0..3 in VGPRs (48 regs), m=4..7 in LDS (12 KB, stride-16B
// ds_read_b128 per row). LN stats from lnstat (no s1/s2 rails). Phase 2 in
// two m-halves (O[4][12]=48 regs). Target <=128 VGPR + 38 KB -> 4 blocks/CU.
// Softmax fixed reference m=0 (exact: shift-invariant, scores ~N(0,0.02^2)).
__global__ __launch_bounds__(256, 4) void k_score(
    const float* __restrict__ tokens, const int* __restrict__ lengths,
    const float* __restrict__ q, const float* __restrict__ lns,
    const float* __restrict__ lnb, const float* __restrict__ lnstat,
    float* __restrict__ plearn, float* __restrict__ ltot) {
  int c = blockIdx.x, b = blockIdx.y;
  int len = clen(lengths[b]);
  int c0 = c * 64;
  if (c0 >= len) return;
  int tid = threadIdx.x, w = tid >> 6, lane = tid & 63;
  int mm2 = lane & 3;

  __shared__ float qs_lds[4][SD];         // 12 KB  qs for m=4..7
  __shared__ float p_lds[4][16][8];       // 2 KB   exp(scores)
  __shared__ float O_lds[SM][SD];         // 24 KB
  __shared__ float l_lds[4][8];

  // init p_lds to 0 (invalid rows contribute p=0)
  {
    float* pf = &p_lds[0][0][0];
    for (int i = tid; i < 512; i += 256) pf[i] = 0.f;
  }

  // ---- q setup: m<4 -> qr regs; m>=4 -> qs_lds (wave 0 writes) ----
  float4 qr[4][3];
  float qs1A, qs1B, qbA, qbB;
  {
    float4 l4[3], lb4[3];
    #pragma unroll
    for (int g = 0; g < 3; ++g) {
      l4[g] = *(const float4*)(lns + g * 256 + lane * 4);
      lb4[g] = *(const float4*)(lnb + g * 256 + lane * 4);
    }
    float qs1r[8], qbr[8];
    #pragma unroll
    for (int m = 0; m < 8; ++m) {
      float s1 = 0.f, sb = 0.f;
      #pragma unroll
      for (int g = 0; g < 3; ++g) {
        float4 qv = *(const float4*)(q + m * SD + g * 256 + lane * 4);
        float4 qs;
        qs.x = qv.x * l4[g].x; qs.y = qv.y * l4[g].y;
        qs.z = qv.z * l4[g].z; qs.w = qv.w * l4[g].w;
        if (m < 4) qr[m][g] = qs;
        else if (w == 0) *(float4*)&qs_lds[m - 4][g * 256 + lane * 4] = qs;
        s1 += qs.x + qs.y + qs.z + qs.w;
        sb += qv.x * lb4[g].x + qv.y * lb4[g].y + qv.z * lb4[g].z + qv.w * lb4[g].w;
      }
      #pragma unroll
      for (int o = 32; o; o >>= 1) { s1 += __shfl_xor(s1, o, 64); sb += __shfl_xor(sb, o, 64); }
      qs1r[m] = s1; qbr[m] = sb;
    }
    qs1A = qs1r[0]; qbA = qbr[0]; qs1B = qs1r[4]; qbB = qbr[4];
    #pragma unroll
    for (int m = 1; m < 4; ++m) {
      qs1A = (mm2 == m) ? qs1r[m] : qs1A;
      qbA  = (mm2 == m) ? qbr[m]  : qbA;
      qs1B = (mm2 == m) ? qs1r[4 + m] : qs1B;
      qbB  = (mm2 == m) ? qbr[4 + m]  : qbB;
    }
  }
  __syncthreads();  // p_lds init + qs_lds staging visible

  // ---- phase 1: scores -> exp (x once; 2-deep pipelined loads) ----
  int srow = c0 + w * 16;
  int smax = len - srow; if (smax > 16) smax = 16; if (smax < 0) smax = 0;
  const float* xrow = tokens + ((size_t)b * TOK_ROW + 1 + srow) * SD;
  const float* lrow = lnstat + ((size_t)b * SS + srow) * 2;
  float lA = 0.f, lB = 0.f;

  float4 nx0 = {}, nx1 = {}, nx2 = {};
  float nmu = 0.f, nrs = 0.f;
  if (smax > 0) {
    nx0 = *(const float4*)(xrow + lane * 4);
    nx1 = *(const float4*)(xrow + 256 + lane * 4);
    nx2 = *(const float4*)(xrow + 512 + lane * 4);
    nmu = lrow[0]; nrs = lrow[1];
  }
  for (int i = 0; i < smax; ++i) {
    float4 x0 = nx0, x1 = nx1, x2 = nx2;
    float mu = nmu, rstd = nrs;
    if (i + 1 < smax) {
      const float* xq = xrow + (size_t)(i + 1) * SD;
      nx0 = *(const float4*)(xq + lane * 4);
      nx1 = *(const float4*)(xq + 256 + lane * 4);
      nx2 = *(const float4*)(xq + 512 + lane * 4);
      nmu = lrow[2 * (i + 1)]; nrs = lrow[2 * (i + 1) + 1];
    }
    float xv[12] = {x0.x, x0.y, x0.z, x0.w, x1.x, x1.y, x1.z, x1.w,
                    x2.x, x2.y, x2.z, x2.w};
    float d[8];
    #pragma unroll
    for (int mq = 0; mq < 4; ++mq) {
      float4 a0 = qr[mq][0], a1 = qr[mq][1], a2 = qr[mq][2];
      d[mq] = a0.x * xv[0] + a0.y * xv[1] + a0.z * xv[2] + a0.w * xv[3]
            + a1.x * xv[4] + a1.y * xv[5] + a1.z * xv[6] + a1.w * xv[7]
            + a2.x * xv[8] + a2.y * xv[9] + a2.z * xv[10] + a2.w * xv[11];
    }
    #pragma unroll
    for (int mq = 0; mq < 4; ++mq) {
      float acc = 0.f;
      #pragma unroll
      for (int g = 0; g < 3; ++g) {
        float4 qv = *(const float4*)&qs_lds[mq][g * 256 + lane * 4];
        acc += qv.x * xv[g*4] + qv.y * xv[g*4+1] + qv.z * xv[g*4+2] + qv.w * xv[g*4+3];
      }
      d[4 + mq] = acc;
    }
    // quad butterfly {1,2}, select by lane&3, then {4,8,16,32}
    #pragma unroll
    for (int o = 1; o <= 2; o <<= 1)
      #pragma unroll
      for (int m = 0; m < 8; ++m) d[m] += __shfl_xor(d[m], o, 64);
    float uA = d[0], uB = d[4];
    #pragma unroll
    for (int m = 1; m < 4; ++m) {
      uA = (mm2 == m) ? d[m] : uA;
      uB = (mm2 == m) ? d[4 + m] : uB;
    }
    #pragma unroll
    for (int o = 4; o <= 32; o <<= 1) {
      uA += __shfl_xor(uA, o, 64);
      uB += __shfl_xor(uB, o, 64);
    }
    float peA = __expf((rstd * uA - rstd * mu * qs1A + qbA) * 0.03608439182435161f);
    float peB = __expf((rstd * uB - rstd * mu * qs1B + qbB) * 0.03608439182435161f);
    lA += peA; lB += peB;
    if (lane < 4) { p_lds[w][i][lane] = peA; p_lds[w][i][4 + lane] = peB; }
  }
  if (lane < 4) { l_lds[w][lane] = lA; l_lds[w][4 + lane] = lB; }
  __syncthreads();
  if (tid < 8)
    atomicAdd(&ltot[b * 8 + tid],
              l_lds[0][tid] + l_lds[1][tid] + l_lds[2][tid] + l_lds[3][tid]);

  // ---- phase 2: O (two m-halves; x re-read L2-hot, 2-deep pipe) ----
  #pragma unroll
  for (int half = 0; half < 2; ++half) {
    float O[4][12];
    #pragma unroll
    for (int mq = 0; mq < 4; ++mq)
      #pragma unroll
      for (int j = 0; j < 12; ++j) O[mq][j] = 0.f;
    float4 a0v = {}, a1v = {}, a2v = {}, b0v = {}, b1v = {}, b2v = {};
    if (smax > 0) {
      a0v = *(const float4*)(xrow + lane * 4);
      a1v = *(const float4*)(xrow + 256 + lane * 4);
      a2v = *(const float4*)(xrow + 512 + lane * 4);
    }
    if (smax > 1) {
      const float* xq = xrow + SD;
      b0v = *(const float4*)(xq + lane * 4);
      b1v = *(const float4*)(xq + 256 + lane * 4);
      b2v = *(const float4*)(xq + 512 + lane * 4);
    }
    for (int i = 0; i < smax; ++i) {
      float4 x0 = a0v, x1 = a1v, x2 = a2v;
      a0v = b0v; a1v = b1v; a2v = b2v;
      if (i + 2 < smax) {
        const float* xq = xrow + (size_t)(i + 2) * SD;
        b0v = *(const float4*)(xq + lane * 4);
        b1v = *(const float4*)(xq + 256 + lane * 4);
        b2v = *(const float4*)(xq + 512 + lane * 4);
      }
      float xv[12] = {x0.x, x0.y, x0.z, x0.w, x1.x, x1.y, x1.z, x1.w,
                      x2.x, x2.y, x2.z, x2.w};
      float4 pa = *(const float4*)&p_lds[w][i][half * 4];
      float pm[4] = {pa.x, pa.y, pa.z, pa.w};
      #pragma unroll
      for (int mq = 0; mq < 4; ++mq)
        #pragma unroll
        for (int j = 0; j < 12; ++j) O[mq][j] += pm[mq] * xv[j];
    }
    // accumulate this half's O across waves into O_lds[half*4 .. half*4+3]
    #pragma unroll
    for (int r = 0; r < 4; ++r) {
      if (w == r) {
        #pragma unroll
        for (int mq = 0; mq < 4; ++mq)
          #pragma unroll
          for (int g = 0; g < 3; ++g) {
            int dd = g * 256 + lane * 4;
            float4 mine = make_float4(O[mq][g*4], O[mq][g*4+1], O[mq][g*4+2], O[mq][g*4+3]);
            if (r == 0) {
              *(float4*)&O_lds[half * 4 + mq][dd] = mine;
            } else {
              float4 cur = *(float4*)&O_lds[half * 4 + mq][dd];
              cur.x += mine.x; cur.y += mine.y; cur.z += mine.z; cur.w += mine.w;
              *(float4*)&O_lds[half * 4 + mq][dd] = cur;
            }
          }
      }
      __syncthreads();
    }
  }

  // ---- atomic writeout: O -> plearn (fadd); clf passthrough ----
  {
    const float* of = &O_lds[0][0];
    for (int j = tid; j < 6144; j += 256)
      atomicAdd(&plearn[(size_t)b * 6912 + j], of[j]);
  }
  if (c == 0)
    for (int dd = tid; dd < 768; dd += 256)
      plearn[(size_t)b * 6912 + 6144 + dd] = tokens[(size_t)b * TOK_ROW * SD + dd];
}

// ============ split-K GEMM partial: (16 x K) @ (K x 768), k-tile = 128 ========
// mode 0: X = ptradS (stat-major, decode/normalize at staging; uniform per block)
// mode 1: X = plearn (merged cols x 1/ltot; clf raw; uniform per block)
// mode 2: X = plain row-major [16][K]
// epi  0: write partials to P[(kt*16+b2)*768 + n]
// epi  1: atomicAdd into P[b2*1536 + n] (out pre-initialized with bias)
__global__ __launch_bounds__(256) void gemm_partial(
    const float* __restrict__ XA, const float* __restrict__ WA, int ktA, float* __restrict__ PA,
    const float* __restrict__ XB, const float* __restrict__ WB, float* __restrict__ PB,
    const int* __restrict__ lengths, const float* __restrict__ ltot,
    int modeA, int modeB, int epi) {
  int nt = blockIdx.x, ky = blockIdx.y;
  const float *X, *W; float* P; int kt, ktN, mode;
  if (ky < ktA) { X = XA; W = WA; P = PA; kt = ky; ktN = ktA; mode = modeA; }
  else { X = XB; W = WB; P = PB; kt = ky - ktA; ktN = gridDim.y - ktA; mode = modeB; }
  int K = ktN * 128;
  int k0 = kt * 128;
  __shared__ __align__(16) float xt[128 * 20];
  __shared__ float red[4][64][17];
  int tid = threadIdx.x;
  int kk = tid & 127, half = tid >> 7;
  #pragma unroll
  for (int u = 0; u < 8; ++u) {
    int b2 = half * 8 + u;
    float f;
    if (mode == 0) {
      int s = kt / 6;                             // stat, uniform per block
      f = X[s * 12288 + b2 * 768 + (k0 - s * 768) + kk];
      if (s == 0) f = f / (float)clen(lengths[b2]);       // mean = sum/len
      else        f = fdec(__float_as_uint(f));           // decode max/min
    } else if (mode == 1) {
      f = X[b2 * 6912 + k0 + kk];
      if (kt < 48) f = f / ltot[b2 * 8 + (k0 / 768)];     // merged / l_total
    } else {
      f = X[b2 * K + k0 + kk];
    }
    xt[kk * 20 + b2] = f;
  }
  __syncthreads();
  int w = tid >> 6, lane = tid & 63;
  int n = nt * 64 + lane;
  float acc[16];
  #pragma unroll
  for (int b2 = 0; b2 < 16; ++b2) acc[b2] = 0.f;
  const float* Wp = W + (size_t)k0 * SD + n;
  #pragma unroll 8
  for (int kj = 0; kj < 32; ++kj) {
    int k = w + kj * 4;
    float wv = Wp[(size_t)k * SD];
    const float4* xr = reinterpret_cast<const float4*>(xt + k * 20);
    float4 a0 = xr[0], a1 = xr[1], a2 = xr[2], a3 = xr[3];
    acc[0] += wv * a0.x; acc[1] += wv * a0.y; acc[2] += wv * a0.z; acc[3] += wv * a0.w;
    acc[4] += wv * a1.x; acc[5] += wv * a1.y; acc[6] += wv * a1.z; acc[7] += wv * a1.w;
    acc[8] += wv * a2.x; acc[9] += wv * a2.y; acc[10] += wv * a2.z; acc[11] += wv * a2.w;
    acc[12] += wv * a3.x; acc[13] += wv * a3.y; acc[14] += wv * a3.z; acc[15] += wv * a3.w;
  }
  #pragma unroll
  for (int b2 = 0; b2 < 16; ++b2) red[w][lane][b2] = acc[b2];
  __syncthreads();
  for (int i = tid; i < 1024; i += 256) {
    int nn = i & 63, b2 = i >> 6;
    float r = red[0][nn][b2] + red[1][nn][b2] + red[2][nn][b2] + red[3][nn][b2];
    if (epi == 0) P[(size_t)(kt * 16 + b2) * SD + nt * 64 + nn] = r;
    else          atomicAdd(&P[b2 * 1536 + nt * 64 + nn], r);
  }
}

// ============ reduce + bias + exact GELU (compile-time trip counts) ===========
__global__ void gelu_reduce(const float* __restrict__ PA, const float* __restrict__ b1a,
                            float* __restrict__ HA, const float* __restrict__ PB,
                            const float* __restrict__ b1b, float* __restrict__ HB) {
  int y = blockIdx.y;
  int j = blockIdx.x * 256 + threadIdx.x;  // < 12288
  float r;
  if (y == 0) {
    r = b1a[j % SD];
    #pragma unroll
    for (int kt = 0; kt < 18; ++kt) r += PA[kt * 12288 + j];
    HA[j] = r * 0.5f * (1.f + erff(r * 0.70710678118654752f));
  } else {
    r = b1b[j % SD];
    #pragma unroll
    for (int kt = 0; kt < 54; ++kt) r += PB[kt * 12288 + j];
    HB[j] = r * 0.5f * (1.f + erff(r * 0.70710678118654752f));
  }
}

extern "C" void kernel_launch(void* const* d_in, const int* in_sizes, int n_in,
                              void* d_out, int out_size, void* d_ws, size_t ws_size,
                              hipStream_t stream) {
  const float* tokens = (const float*)d_in[0];
  const int* lengths  = (const int*)d_in[1];
  const float* q      = (const float*)d_in[2];
  const float* lns    = (const float*)d_in[3];
  const float* lnb    = (const float*)d_in[4];
  const float* w1a    = (const float*)d_in[5];
  const float* b1a    = (const float*)d_in[6];
  const float* w2a    = (const float*)d_in[7];
  const float* b2a    = (const float*)d_in[8];
  const float* w1b    = (const float*)d_in[9];
  const float* b1b    = (const float*)d_in[10];
  const float* w2b    = (const float*)d_in[11];
  const float* b2b    = (const float*)d_in[12];
  float* ws  = (float*)d_ws;
  float* out = (float*)d_out;

  float* ptradS = ws + OFF_PTRADS;
  float* plearn = ws + OFF_PLEARN;
  float* ltot   = ws + OFF_LTOT;
  float* lnstat = ws + OFF_LNSTAT;
  float* p1a    = ws + OFF_P1A;
  float* p1b    = ws + OFF_P1B;
  float* ha     = ws + OFF_HA;
  float* hb     = ws + OFF_HB;

  k_init<<<dim3(128), 256, 0, stream>>>(ws, out, b2a, b2b);
  k_pool<<<dim3(32, 16), 256, 0, stream>>>(tokens, lengths, ptradS, lnstat);
  k_score<<<dim3(32, 16), 256, 0, stream>>>(tokens, lengths, q, lns, lnb, lnstat,
                                            plearn, ltot);
  gemm_partial<<<dim3(12, 72), 256, 0, stream>>>(ptradS, w1a, 18, p1a,
                                                 plearn, w1b, p1b,
                                                 lengths, ltot, 0, 1, 0);
  gelu_reduce<<<dim3(48, 2), 256, 0, stream>>>(p1a, b1a, ha, p1b, b1b, hb);
  gemm_partial<<<dim3(12, 12), 256, 0, stream>>>(ha, w2a, 6, out,
                                                 hb, w2b, out + 768,
                                                 lengths, ltot, 2, 2, 1);
}